// Round 3
// baseline (423.174 us; speedup 1.0000x reference)
//
#include <hip/hip_runtime.h>
#include <hip/hip_bf16.h>
#include <stdint.h>

typedef __attribute__((ext_vector_type(8))) short short8;
typedef __attribute__((ext_vector_type(16))) float floatx16;
typedef unsigned short u16;

#define IN_DIM  1024
#define OUT_DIM 1024
#define NG      11            // spline bases per channel
#define GK      12            // + silu slot
#define KDIM    (IN_DIM * GK) // 12288
#define TOKENS  8192
#define MT      64            // 128-tile M count (fused fallback)
#define BK      96            // fused path: 8 channels x 12 slots
#define PB      104           // fused path padded LDS row stride
#define NOPS    26            // fused path B DMA ops/iter
#define GBK     64            // K elems per tile (4 k-steps of 16)
#define G2R     9             // LDS granules/row: 8 data + 1 pad (odd -> bank rotation)
#define G2OPS   36            // 256 rows * 9 granules / 64 lanes
#define ABUF    (256 * 72)    // u16 elems per LDS buffer (256 rows * 9*8)

__device__ __forceinline__ u16 f2bf(float f) {
  uint32_t u = __float_as_uint(f);
  uint32_t r = (u + 0x7fffu + ((u >> 16) & 1u)) >> 16;  // RNE
  return (u16)r;
}

// ---------------- pack Wt: bf16 [OUT_DIM][KDIM] (unchanged, verified)
__global__ __launch_bounds__(256) void pack_wt_kernel(
    const float* __restrict__ coeff, const float* __restrict__ sb,
    const float* __restrict__ ss_p, u16* __restrict__ Wt)
{
  __shared__ float cf[256 * NG];
  __shared__ __align__(16) u16 st[256 * GK];
  const int tid = threadIdx.x;
  const int b   = blockIdx.x;
  const int o   = b >> 2;
  const int i0  = (b & 3) * 256;
  const float* cbase = coeff + (size_t)o * (IN_DIM * NG) + (size_t)i0 * NG;
#pragma unroll
  for (int p = 0; p < NG; ++p) cf[p * 256 + tid] = cbase[p * 256 + tid];
  const float ss  = ss_p[0];
  const float sbv = sb[(size_t)o * IN_DIM + i0 + tid];
  __syncthreads();
  const float* cp = cf + tid * NG;
  u16 h[GK];
#pragma unroll
  for (int g = 0; g < NG; ++g) h[g] = f2bf(cp[g] * ss);
  h[NG] = f2bf(sbv);
  uint64_t V0 = (uint64_t)h[0] | ((uint64_t)h[1] << 16) | ((uint64_t)h[2] << 32) | ((uint64_t)h[3] << 48);
  uint64_t V1 = (uint64_t)h[4] | ((uint64_t)h[5] << 16) | ((uint64_t)h[6] << 32) | ((uint64_t)h[7] << 48);
  uint64_t V2 = (uint64_t)h[8] | ((uint64_t)h[9] << 16) | ((uint64_t)h[10] << 32) | ((uint64_t)h[11] << 48);
  uint64_t* sp = (uint64_t*)(st + tid * GK);
  sp[0] = V0; sp[1] = V1; sp[2] = V2;
  __syncthreads();
  const uint4* src = (const uint4*)st;
  uint4* dst = (uint4*)(Wt + (size_t)b * (256 * GK));
  dst[tid] = src[tid];
  if (tid < 128) dst[256 + tid] = src[256 + tid];
}

// Closed-form cubic B-spline + silu -> 3 u64 (verified, absmax 0.125)
__device__ __forceinline__ void expand_regs(float x, float g0, float inv_h,
                                            uint64_t& V0, uint64_t& V1, uint64_t& V2)
{
  float t  = (x - g0) * inv_h;
  float fc = floorf(t);
  int   c  = (int)fc;
  float u  = t - fc;
  float u2 = u * u;
  float w1 = 1.0f - u;
  float b0 = (w1 * w1 * w1) * (1.0f / 6.0f);
  float b1 = (0.5f * u - 1.0f) * u2 + (2.0f / 3.0f);
  float b2 = ((-0.5f * u + 0.5f) * u + 0.5f) * u + (1.0f / 6.0f);
  float b3 = (u2 * u) * (1.0f / 6.0f);
  float sil = x / (1.0f + __expf(-x));

  uint64_t P = (uint64_t)f2bf(b0) | ((uint64_t)f2bf(b1) << 16)
             | ((uint64_t)f2bf(b2) << 32) | ((uint64_t)f2bf(b3) << 48);
  int  k  = c - 3;
  bool cv = (c >= 0) && (c <= 13);
  int  kneg = (k < 0) ? -k : 0;
  uint64_t Pc = cv ? (P >> (16 * kneg)) : 0ull;
  uint32_t sh = (uint32_t)(16 * ((k < 0) ? 0 : k));

  V0 = (sh < 64)  ? (Pc << (sh & 63)) : 0ull;
  V1 = (sh == 0)  ? 0ull :
       (sh < 64)  ? (Pc >> ((64 - sh) & 63)) :
       (sh < 128) ? (Pc << ((sh - 64) & 63)) : 0ull;
  V2 = (sh <= 64) ? 0ull :
       (sh < 128) ? (Pc >> ((128 - sh) & 63)) :
                    (Pc << ((sh - 128) & 63));
  V2 = (V2 & 0x0000FFFFFFFFFFFFull) | ((uint64_t)f2bf(sil) << 48);
}

__device__ __forceinline__ void async16(const u16* g, u16* l) {
  __builtin_amdgcn_global_load_lds(
      (const __attribute__((address_space(1))) uint32_t*)g,
      (__attribute__((address_space(3))) uint32_t*)l,
      16, 0, 0);
}

// ---------------- expand X once -> Aexp[TOKENS][KDIM] bf16.
// 4 rows per block (ILP across the LDS funnel + launch amortization).
__global__ __launch_bounds__(256) void expand_x_kernel(
    const float* __restrict__ X, const float* __restrict__ grid,
    u16* __restrict__ Aexp)
{
  __shared__ __align__(16) uint4 st[1536];   // 24576 B = one expanded row
  const int tid = threadIdx.x;
  const float g0    = grid[0];
  const float inv_h = 1.0f / (grid[1] - grid[0]);

  for (int rr = 0; rr < 4; ++rr) {
    const int row = blockIdx.x * 4 + rr;
    float4 xv = *(const float4*)(X + (size_t)row * IN_DIM + tid * 4);
    uint64_t ev[12];
    expand_regs(xv.x, g0, inv_h, ev[0], ev[1], ev[2]);
    expand_regs(xv.y, g0, inv_h, ev[3], ev[4], ev[5]);
    expand_regs(xv.z, g0, inv_h, ev[6], ev[7], ev[8]);
    expand_regs(xv.w, g0, inv_h, ev[9], ev[10], ev[11]);
    if (rr) __syncthreads();   // prior iteration's funnel reads drained
#pragma unroll
    for (int j = 0; j < 6; ++j) {
      uint4 w;
      w.x = (uint32_t)ev[2*j];     w.y = (uint32_t)(ev[2*j] >> 32);
      w.z = (uint32_t)ev[2*j+1];   w.w = (uint32_t)(ev[2*j+1] >> 32);
      st[tid * 6 + j] = w;
    }
    __syncthreads();
    uint4* dst = (uint4*)(Aexp + (size_t)row * KDIM);
#pragma unroll
    for (int j = 0; j < 6; ++j) dst[j * 256 + tid] = st[j * 256 + tid];
  }
}

// ---------------- GEMM v3: 256x256 tile, 8 waves, counted-vmcnt pipeline (T3+T4).
// Raw s_barrier + inline-asm vmcnt(8): stages for tile t+2 issued into the
// buffer freed at tile t's end; vmcnt(8) certifies tile t+1 complete while
// leaving t+2's (>=8-op) batch in flight -> HBM/L3 latency hidden under a
// full tile of MFMA. Pad-granule LDS (G2R=9, stride 144B: bank = 4*((row+c)%8),
// 32 rows -> 8 groups x 4 lanes) = measured-0-conflict layout from round 2.
// LDS 144KB -> 1 block/CU; split-K=2 -> 256 blocks = exactly 1/CU.
// bm = r&31 -> bid%8 = bm%8: the 4 bn-blocks sharing an A strip co-run on one
// XCD (strip 3.15MB < 4MB L2).
__global__ __launch_bounds__(512, 2) void gemm_pre_kernel(
    const u16* __restrict__ A, const u16* __restrict__ Wt,
    float* __restrict__ out, float* __restrict__ part, int k_iters)
{
  __shared__ __align__(16) u16 As[2 * ABUF];   // 73728 B
  __shared__ __align__(16) u16 Bs[2 * ABUF];   // 73728 B

  const int tid  = threadIdx.x;
  const int lane = tid & 63;
  const int wave = tid >> 6;              // 0..7
  const int s    = blockIdx.x >> 7;       // 128 blocks per K-split
  const int r    = blockIdx.x & 127;
  const int bm   = r & 31;
  const int bn   = r >> 5;
  const int wm   = (wave >> 2) * 128;     // 2 M-warps
  const int wn   = (wave & 3) * 64;       // 4 N-warps
  const int l31  = lane & 31;
  const int g8   = lane >> 5;

  floatx16 acc[4][2];
#pragma unroll
  for (int a = 0; a < 4; ++a)
#pragma unroll
    for (int b = 0; b < 2; ++b)
#pragma unroll
      for (int rr = 0; rr < 16; ++rr) acc[a][b][rr] = 0.f;

  // DMA setup: op o (= wave + 8j, o < G2OPS) moves granules [64o, 64o+64).
  // lane: gidx = 64o+lane; row = gidx/9; chunk = gidx%9; chunk 8 = pad-dup.
  const size_t k0 = (size_t)s * k_iters * GBK;
  const u16* asrc[5]; const u16* bsrc[5]; int doff[5]; bool act[5];
#pragma unroll
  for (int j = 0; j < 5; ++j) {
    int o  = wave + 8 * j;
    act[j] = (o < G2OPS);
    int oc = act[j] ? o : (G2OPS - 1);
    int gidx  = oc * 64 + lane;
    int row   = gidx / 9;
    int chunk = gidx - row * 9;
    int c8    = (chunk == 8) ? 0 : chunk;
    asrc[j] = A  + (size_t)(bm * 256 + row) * KDIM + k0 + c8 * 8;
    bsrc[j] = Wt + (size_t)(bn * 256 + row) * KDIM + k0 + c8 * 8;
    doff[j] = oc * 512;   // 64 granules = 1024 B per op
  }

  const int NT = k_iters;

  // prologue: tile 0 -> buf0 (drain), tile 1 -> buf1 (left in flight)
#pragma unroll
  for (int j = 0; j < 5; ++j) if (act[j]) async16(asrc[j], As + doff[j]);
#pragma unroll
  for (int j = 0; j < 5; ++j) if (act[j]) async16(bsrc[j], Bs + doff[j]);
  asm volatile("s_waitcnt vmcnt(0)" ::: "memory");
  __builtin_amdgcn_s_barrier();
  __builtin_amdgcn_sched_barrier(0);
#pragma unroll
  for (int j = 0; j < 5; ++j) if (act[j]) async16(asrc[j] + GBK, As + ABUF + doff[j]);
#pragma unroll
  for (int j = 0; j < 5; ++j) if (act[j]) async16(bsrc[j] + GBK, Bs + ABUF + doff[j]);

  for (int t = 0; t < NT; ++t) {
    const u16* Ab = As + (t & 1) * ABUF;
    const u16* Bb = Bs + (t & 1) * ABUF;

    __builtin_amdgcn_s_setprio(1);
#pragma unroll
    for (int ks = 0; ks < 4; ++ks) {
      short8 bf0 = *(const short8*)&Bb[(wn +      l31) * 72 + (2 * ks + g8) * 8];
      short8 bf1 = *(const short8*)&Bb[(wn + 32 + l31) * 72 + (2 * ks + g8) * 8];
#pragma unroll
      for (int m = 0; m < 4; ++m) {
        short8 af = *(const short8*)&Ab[(wm + m * 32 + l31) * 72 + (2 * ks + g8) * 8];
        acc[m][0] = __builtin_amdgcn_mfma_f32_32x32x16_bf16(af, bf0, acc[m][0], 0, 0, 0);
        acc[m][1] = __builtin_amdgcn_mfma_f32_32x32x16_bf16(af, bf1, acc[m][1], 0, 0, 0);
      }
    }
    __builtin_amdgcn_s_setprio(0);

    __builtin_amdgcn_s_barrier();          // all waves done reading buf (t&1)
    __builtin_amdgcn_sched_barrier(0);
    if (t + 2 < NT) {
      u16* Ad = As + (t & 1) * ABUF;       // just-freed buffer
      u16* Bd = Bs + (t & 1) * ABUF;
      const size_t ko = (size_t)(t + 2) * GBK;
#pragma unroll
      for (int j = 0; j < 5; ++j) if (act[j]) async16(asrc[j] + ko, Ad + doff[j]);
#pragma unroll
      for (int j = 0; j < 5; ++j) if (act[j]) async16(bsrc[j] + ko, Bd + doff[j]);
      asm volatile("s_waitcnt vmcnt(8)" ::: "memory");   // tile t+1 certified complete
    } else {
      asm volatile("s_waitcnt vmcnt(0)" ::: "memory");
    }
    __builtin_amdgcn_s_barrier();          // buf (t+1)&1 ready for next iter
    __builtin_amdgcn_sched_barrier(0);
  }

  // C/D map (m74/m101-verified): col=lane&31, row=(reg&3)+8*(reg>>2)+4*(lane>>5)
  float* op = (s == 0) ? out : part;
#pragma unroll
  for (int m = 0; m < 4; ++m)
#pragma unroll
    for (int n = 0; n < 2; ++n) {
      const int row0 = bm * 256 + wm + m * 32 + 4 * g8;
      const int col  = bn * 256 + wn + n * 32 + l31;
#pragma unroll
      for (int reg = 0; reg < 16; ++reg) {
        int row = row0 + (reg & 3) + 8 * (reg >> 2);
        op[(size_t)row * OUT_DIM + col] = acc[m][n][reg];
      }
    }
}

// out += part, float4-vectorized
__global__ __launch_bounds__(256) void reduce_kernel(
    float* __restrict__ out, const float* __restrict__ part)
{
  size_t i = (size_t)blockIdx.x * 256 + threadIdx.x;
  float4* o = (float4*)out;
  const float4* p = (const float4*)part;
  float4 a = o[i], b = p[i];
  a.x += b.x; a.y += b.y; a.z += b.z; a.w += b.w;
  o[i] = a;
}

// ---------------- OLD fused path (fallback when workspace too small) ----------------
__global__ __launch_bounds__(256, 3) void gemm_fused_kernel(
    const float* __restrict__ X, const float* __restrict__ grid,
    const u16* __restrict__ Wt, float* __restrict__ out, float* __restrict__ part,
    int k_iters)
{
  __shared__ __align__(16) u16 As[128 * PB];
  __shared__ __align__(16) u16 Bs[128 * PB];

  const int tid  = threadIdx.x;
  const int lane = tid & 63;
  const int wave = tid >> 6;
  const int mt8  = MT * 8;
  const int s    = blockIdx.x / mt8;
  const int r    = blockIdx.x - s * mt8;
  const int bm   = r % MT;
  const int bn   = r / MT;
  const int wm = (wave >> 1) * 64;
  const int wn = (wave & 1) * 64;

  const float g0    = grid[0];
  const float inv_h = 1.0f / (grid[1] - grid[0]);

  floatx16 acc[2][2];
#pragma unroll
  for (int a = 0; a < 2; ++a)
#pragma unroll
    for (int b = 0; b < 2; ++b)
#pragma unroll
      for (int rr = 0; rr < 16; ++rr) acc[a][b][rr] = 0.f;

  const int kb_u16 = s * k_iters * BK;
  const u16* bsrc[7];
  u16*       bdst[7];
  bool       bact[7];
#pragma unroll
  for (int j = 0; j < 7; ++j) {
    int o  = wave + 4 * j;
    bact[j] = (o < NOPS);
    int oc = bact[j] ? o : (NOPS - 1);
    int gidx  = oc * 64 + lane;
    int row   = gidx / 13;
    int chunk = gidx - row * 13;
    int c8    = (chunk == 12) ? 0 : chunk;
    bsrc[j] = Wt + (size_t)(bn * 128 + row) * KDIM + kb_u16 + c8 * 8;
    bdst[j] = Bs + oc * 512;
  }

  const int arow = tid & 127;
  const int half = tid >> 7;
  const float* xp = X + (size_t)(bm * 128 + arow) * IN_DIM + s * (k_iters * 8) + half * 4;
  uint4* awp = (uint4*)(As + arow * PB + half * 48);

  const int l31 = lane & 31;
  const int g   = lane >> 5;

  float4 xv = *(const float4*)xp;

  for (int it = 0; it < k_iters; ++it) {
    uint64_t ev[12];
    expand_regs(xv.x, g0, inv_h, ev[0], ev[1], ev[2]);
    expand_regs(xv.y, g0, inv_h, ev[3], ev[4], ev[5]);
    expand_regs(xv.z, g0, inv_h, ev[6], ev[7], ev[8]);
    expand_regs(xv.w, g0, inv_h, ev[9], ev[10], ev[11]);
    if (it + 1 < k_iters) xv = *(const float4*)(xp + (size_t)(it + 1) * 8);

    __syncthreads();

#pragma unroll
    for (int j = 0; j < 7; ++j)
      if (bact[j]) async16(bsrc[j] + (size_t)it * BK, bdst[j]);

#pragma unroll
    for (int j = 0; j < 6; ++j) {
      uint4 w;
      w.x = (uint32_t)ev[2*j];     w.y = (uint32_t)(ev[2*j] >> 32);
      w.z = (uint32_t)ev[2*j+1];   w.w = (uint32_t)(ev[2*j+1] >> 32);
      awp[j] = w;
    }

    __syncthreads();

#pragma unroll
    for (int t = 0; t < 6; ++t) {
      const int cc = 2 * t + g;
      short8 af[2], bf[2];
#pragma unroll
      for (int ss2 = 0; ss2 < 2; ++ss2) {
        af[ss2] = *(const short8*)&As[(wm + ss2 * 32 + l31) * PB + cc * 8];
        bf[ss2] = *(const short8*)&Bs[(wn + ss2 * 32 + l31) * PB + cc * 8];
      }
#pragma unroll
      for (int sm = 0; sm < 2; ++sm)
#pragma unroll
        for (int sn = 0; sn < 2; ++sn)
          acc[sm][sn] = __builtin_amdgcn_mfma_f32_32x32x16_bf16(af[sm], bf[sn], acc[sm][sn], 0, 0, 0);
    }
  }
  __syncthreads();

  float* op = (s == 0) ? out : part;
#pragma unroll
  for (int sm = 0; sm < 2; ++sm)
#pragma unroll
    for (int sn = 0; sn < 2; ++sn) {
      const int row0 = bm * 128 + wm + sm * 32 + 4 * g;
      const int col  = bn * 128 + wn + sn * 32 + l31;
#pragma unroll
      for (int reg = 0; reg < 16; ++reg) {
        int row = row0 + (reg & 3) + 8 * (reg >> 2);
        op[(size_t)row * OUT_DIM + col] = acc[sm][sn][reg];
      }
    }
}

extern "C" void kernel_launch(void* const* d_in, const int* in_sizes, int n_in,
                              void* d_out, int out_size, void* d_ws, size_t ws_size,
                              hipStream_t stream) {
  const float* x     = (const float*)d_in[0];
  const float* grid  = (const float*)d_in[1];
  const float* coeff = (const float*)d_in[2];
  const float* sb    = (const float*)d_in[3];
  const float* ss    = (const float*)d_in[4];
  float* out = (float*)d_out;

  u16* Wt = (u16*)d_ws;
  const size_t wt_bytes   = (size_t)OUT_DIM * KDIM * 2;     // 25.2 MB
  const size_t aexp_bytes = (size_t)TOKENS * KDIM * 2;      // 201.3 MB
  const size_t part_bytes = (size_t)TOKENS * OUT_DIM * 4;   // 33.6 MB

  pack_wt_kernel<<<(OUT_DIM * IN_DIM) / 256, 256, 0, stream>>>(coeff, sb, ss, Wt);

  if (ws_size >= wt_bytes + aexp_bytes + part_bytes) {
    // precompute Aexp; 256x256-tile pipelined GEMM, split-K=2: 256 blocks = 1/CU
    u16*   Aexp = (u16*)((char*)d_ws + wt_bytes);
    float* part = (float*)((char*)d_ws + wt_bytes + aexp_bytes);
    expand_x_kernel<<<TOKENS / 4, 256, 0, stream>>>(x, grid, Aexp);
    gemm_pre_kernel<<<128 * 2, 512, 0, stream>>>(Aexp, Wt, out, part, 96);
    reduce_kernel<<<(TOKENS * OUT_DIM / 4) / 256, 256, 0, stream>>>(out, part);
  } else if (ws_size >= wt_bytes + aexp_bytes) {
    // precompute Aexp, no split (s==0 -> direct out), 128 blocks full-K
    u16* Aexp = (u16*)((char*)d_ws + wt_bytes);
    expand_x_kernel<<<TOKENS / 4, 256, 0, stream>>>(x, grid, Aexp);
    gemm_pre_kernel<<<128, 512, 0, stream>>>(Aexp, Wt, out, nullptr, 192);
  } else if (ws_size >= wt_bytes + part_bytes) {
    // old fused split-K=2
    float* part = (float*)((char*)d_ws + wt_bytes);
    gemm_fused_kernel<<<MT * 8 * 2, 256, 0, stream>>>(x, grid, Wt, out, part, 64);
    reduce_kernel<<<(TOKENS * OUT_DIM / 4) / 256, 256, 0, stream>>>(out, part);
  } else {
    gemm_fused_kernel<<<MT * 8, 256, 0, stream>>>(x, grid, Wt, out, nullptr, 128);
  }
}

// Round 4
// 368.263 us; speedup vs baseline: 1.1491x; 1.1491x over previous
//
#include <hip/hip_runtime.h>
#include <hip/hip_bf16.h>
#include <stdint.h>

typedef __attribute__((ext_vector_type(8))) short short8;
typedef __attribute__((ext_vector_type(16))) float floatx16;
typedef unsigned short u16;

#define IN_DIM  1024
#define OUT_DIM 1024
#define NG      11            // spline bases per channel
#define GK      12            // + silu slot
#define KDIM    (IN_DIM * GK) // 12288
#define TOKENS  8192
#define MT      64            // 128-tile M count (fused fallback)
#define BK      96            // fused path: 8 channels x 12 slots
#define PB      104           // fused path padded LDS row stride
#define NOPS    26            // fused path B DMA ops/iter
#define GBK     64            // K elems per tile (4 k-steps of 16)
#define G2R     9             // LDS granules/row: 8 data + 1 pad (odd -> bank rotation)
#define G2OPS   36            // 256 rows * 9 granules / 64 lanes (per operand)
#define ABUF    (256 * 72)    // u16 elems per LDS buffer (256 rows * 9*8)

__device__ __forceinline__ u16 f2bf(float f) {
  uint32_t u = __float_as_uint(f);
  uint32_t r = (u + 0x7fffu + ((u >> 16) & 1u)) >> 16;  // RNE
  return (u16)r;
}

// ---------------- pack Wt: bf16 [OUT_DIM][KDIM] (unchanged, verified)
__global__ __launch_bounds__(256) void pack_wt_kernel(
    const float* __restrict__ coeff, const float* __restrict__ sb,
    const float* __restrict__ ss_p, u16* __restrict__ Wt)
{
  __shared__ float cf[256 * NG];
  __shared__ __align__(16) u16 st[256 * GK];
  const int tid = threadIdx.x;
  const int b   = blockIdx.x;
  const int o   = b >> 2;
  const int i0  = (b & 3) * 256;
  const float* cbase = coeff + (size_t)o * (IN_DIM * NG) + (size_t)i0 * NG;
#pragma unroll
  for (int p = 0; p < NG; ++p) cf[p * 256 + tid] = cbase[p * 256 + tid];
  const float ss  = ss_p[0];
  const float sbv = sb[(size_t)o * IN_DIM + i0 + tid];
  __syncthreads();
  const float* cp = cf + tid * NG;
  u16 h[GK];
#pragma unroll
  for (int g = 0; g < NG; ++g) h[g] = f2bf(cp[g] * ss);
  h[NG] = f2bf(sbv);
  uint64_t V0 = (uint64_t)h[0] | ((uint64_t)h[1] << 16) | ((uint64_t)h[2] << 32) | ((uint64_t)h[3] << 48);
  uint64_t V1 = (uint64_t)h[4] | ((uint64_t)h[5] << 16) | ((uint64_t)h[6] << 32) | ((uint64_t)h[7] << 48);
  uint64_t V2 = (uint64_t)h[8] | ((uint64_t)h[9] << 16) | ((uint64_t)h[10] << 32) | ((uint64_t)h[11] << 48);
  uint64_t* sp = (uint64_t*)(st + tid * GK);
  sp[0] = V0; sp[1] = V1; sp[2] = V2;
  __syncthreads();
  const uint4* src = (const uint4*)st;
  uint4* dst = (uint4*)(Wt + (size_t)b * (256 * GK));
  dst[tid] = src[tid];
  if (tid < 128) dst[256 + tid] = src[256 + tid];
}

// Closed-form cubic B-spline + silu -> 3 u64 (verified, absmax 0.125)
__device__ __forceinline__ void expand_regs(float x, float g0, float inv_h,
                                            uint64_t& V0, uint64_t& V1, uint64_t& V2)
{
  float t  = (x - g0) * inv_h;
  float fc = floorf(t);
  int   c  = (int)fc;
  float u  = t - fc;
  float u2 = u * u;
  float w1 = 1.0f - u;
  float b0 = (w1 * w1 * w1) * (1.0f / 6.0f);
  float b1 = (0.5f * u - 1.0f) * u2 + (2.0f / 3.0f);
  float b2 = ((-0.5f * u + 0.5f) * u + 0.5f) * u + (1.0f / 6.0f);
  float b3 = (u2 * u) * (1.0f / 6.0f);
  float sil = x / (1.0f + __expf(-x));

  uint64_t P = (uint64_t)f2bf(b0) | ((uint64_t)f2bf(b1) << 16)
             | ((uint64_t)f2bf(b2) << 32) | ((uint64_t)f2bf(b3) << 48);
  int  k  = c - 3;
  bool cv = (c >= 0) && (c <= 13);
  int  kneg = (k < 0) ? -k : 0;
  uint64_t Pc = cv ? (P >> (16 * kneg)) : 0ull;
  uint32_t sh = (uint32_t)(16 * ((k < 0) ? 0 : k));

  V0 = (sh < 64)  ? (Pc << (sh & 63)) : 0ull;
  V1 = (sh == 0)  ? 0ull :
       (sh < 64)  ? (Pc >> ((64 - sh) & 63)) :
       (sh < 128) ? (Pc << ((sh - 64) & 63)) : 0ull;
  V2 = (sh <= 64) ? 0ull :
       (sh < 128) ? (Pc >> ((128 - sh) & 63)) :
                    (Pc << ((sh - 128) & 63));
  V2 = (V2 & 0x0000FFFFFFFFFFFFull) | ((uint64_t)f2bf(sil) << 48);
}

__device__ __forceinline__ void async16(const u16* g, u16* l) {
  __builtin_amdgcn_global_load_lds(
      (const __attribute__((address_space(1))) uint32_t*)g,
      (__attribute__((address_space(3))) uint32_t*)l,
      16, 0, 0);
}

// ---------------- expand X once -> Aexp[TOKENS][KDIM] bf16 (4 rows/block)
__global__ __launch_bounds__(256) void expand_x_kernel(
    const float* __restrict__ X, const float* __restrict__ grid,
    u16* __restrict__ Aexp)
{
  __shared__ __align__(16) uint4 st[1536];   // 24576 B = one expanded row
  const int tid = threadIdx.x;
  const float g0    = grid[0];
  const float inv_h = 1.0f / (grid[1] - grid[0]);

  for (int rr = 0; rr < 4; ++rr) {
    const int row = blockIdx.x * 4 + rr;
    float4 xv = *(const float4*)(X + (size_t)row * IN_DIM + tid * 4);
    uint64_t ev[12];
    expand_regs(xv.x, g0, inv_h, ev[0], ev[1], ev[2]);
    expand_regs(xv.y, g0, inv_h, ev[3], ev[4], ev[5]);
    expand_regs(xv.z, g0, inv_h, ev[6], ev[7], ev[8]);
    expand_regs(xv.w, g0, inv_h, ev[9], ev[10], ev[11]);
    if (rr) __syncthreads();   // prior iteration's funnel reads drained
#pragma unroll
    for (int j = 0; j < 6; ++j) {
      uint4 w;
      w.x = (uint32_t)ev[2*j];     w.y = (uint32_t)(ev[2*j] >> 32);
      w.z = (uint32_t)ev[2*j+1];   w.w = (uint32_t)(ev[2*j+1] >> 32);
      st[tid * 6 + j] = w;
    }
    __syncthreads();
    uint4* dst = (uint4*)(Aexp + (size_t)row * KDIM);
#pragma unroll
    for (int j = 0; j < 6; ++j) dst[j * 256 + tid] = st[j * 256 + tid];
  }
}

// ---------------- GEMM v4: 256x256, 8 waves, counted-vmcnt pipeline — FIXED.
// Round-3 bug: A/B DMA split separately gave waves 10 or 8 ops/tile, so
// vmcnt(8) on the 10-op waves waited on 2 freshly-issued t+2 loads every tile
// (full memory latency inside the barrier pair -> MfmaUtil stuck at 33%).
// Fix: combined op index q = wave + 8j, j<9 over 72 ops (36 A + 36 B) ->
// exactly 9 ops per wave; vmcnt(9) leaves precisely tile t+2 in flight and
// certifies tile t+1 (T4: N = next tile's in-flight count).
// Single LDS array: A bufs at [0],[ABUF]; B bufs at [2*ABUF],[3*ABUF].
// Pad-granule layout (9 granules/row, 144B stride) = measured-0-conflict.
// bm = r&31 -> bid%8 = bm%8: bn-blocks sharing an A strip co-run on one XCD.
__global__ __launch_bounds__(512, 2) void gemm_pre_kernel(
    const u16* __restrict__ A, const u16* __restrict__ Wt,
    float* __restrict__ out, float* __restrict__ part, int k_iters)
{
  __shared__ __align__(16) u16 S[4 * ABUF];   // 147456 B

  const int tid  = threadIdx.x;
  const int lane = tid & 63;
  const int wave = tid >> 6;              // 0..7
  const int s    = blockIdx.x >> 7;       // 128 blocks per K-split
  const int r    = blockIdx.x & 127;
  const int bm   = r & 31;
  const int bn   = r >> 5;
  const int wm   = (wave >> 2) * 128;     // 2 M-warps
  const int wn   = (wave & 3) * 64;       // 4 N-warps
  const int l31  = lane & 31;
  const int g8   = lane >> 5;

  floatx16 acc[4][2];
#pragma unroll
  for (int a = 0; a < 4; ++a)
#pragma unroll
    for (int b = 0; b < 2; ++b)
#pragma unroll
      for (int rr = 0; rr < 16; ++rr) acc[a][b][rr] = 0.f;

  // DMA setup: combined op q = wave + 8j (j<9, q<72): q<36 -> A granule-op q,
  // else B granule-op q-36. lane: gidx = oq*64+lane; row = gidx/9;
  // chunk = gidx%9; chunk 8 = pad -> harmless dup of chunk 0.
  const size_t k0 = (size_t)s * k_iters * GBK;
  const u16* src[9]; int dof[9];
#pragma unroll
  for (int j = 0; j < 9; ++j) {
    int q    = wave + 8 * j;
    bool isA = (q < 36);
    int oq   = isA ? q : q - 36;
    int gidx  = oq * 64 + lane;
    int row   = gidx / 9;
    int chunk = gidx - row * 9;
    int c8    = (chunk == 8) ? 0 : chunk;
    src[j] = (isA ? A + (size_t)(bm * 256 + row) * KDIM
                  : Wt + (size_t)(bn * 256 + row) * KDIM) + k0 + c8 * 8;
    dof[j] = (isA ? 0 : 2 * ABUF) + oq * 512;   // 64 granules = 1024 B per op
  }

  const int NT = k_iters;

  // prologue: tile 0 -> parity 0 (drain), tile 1 -> parity 1 (left in flight)
#pragma unroll
  for (int j = 0; j < 9; ++j) async16(src[j], S + dof[j]);
  asm volatile("s_waitcnt vmcnt(0)" ::: "memory");
  __builtin_amdgcn_s_barrier();
  __builtin_amdgcn_sched_barrier(0);
#pragma unroll
  for (int j = 0; j < 9; ++j) async16(src[j] + GBK, S + ABUF + dof[j]);

  for (int t = 0; t < NT; ++t) {
    const u16* Ab = S + (t & 1) * ABUF;
    const u16* Bb = S + 2 * ABUF + (t & 1) * ABUF;

    __builtin_amdgcn_s_setprio(1);
#pragma unroll
    for (int ks = 0; ks < 4; ++ks) {
      short8 bf0 = *(const short8*)&Bb[(wn +      l31) * 72 + (2 * ks + g8) * 8];
      short8 bf1 = *(const short8*)&Bb[(wn + 32 + l31) * 72 + (2 * ks + g8) * 8];
#pragma unroll
      for (int m = 0; m < 4; ++m) {
        short8 af = *(const short8*)&Ab[(wm + m * 32 + l31) * 72 + (2 * ks + g8) * 8];
        acc[m][0] = __builtin_amdgcn_mfma_f32_32x32x16_bf16(af, bf0, acc[m][0], 0, 0, 0);
        acc[m][1] = __builtin_amdgcn_mfma_f32_32x32x16_bf16(af, bf1, acc[m][1], 0, 0, 0);
      }
    }
    __builtin_amdgcn_s_setprio(0);

    __builtin_amdgcn_s_barrier();          // all waves done reading parity (t&1)
    __builtin_amdgcn_sched_barrier(0);
    if (t + 2 < NT) {
      u16* D = S + (t & 1) * ABUF;         // just-freed parity
      const size_t ko = (size_t)(t + 2) * GBK;
#pragma unroll
      for (int j = 0; j < 9; ++j) async16(src[j] + ko, D + dof[j]);
      asm volatile("s_waitcnt vmcnt(9)" ::: "memory");   // t+1 certified; t+2 in flight
    } else {
      asm volatile("s_waitcnt vmcnt(0)" ::: "memory");
    }
    __builtin_amdgcn_s_barrier();          // parity (t+1)&1 ready for next iter
    __builtin_amdgcn_sched_barrier(0);
  }

  // C/D map (m74/m101-verified): col=lane&31, row=(reg&3)+8*(reg>>2)+4*(lane>>5)
  float* op = (s == 0) ? out : part;
#pragma unroll
  for (int m = 0; m < 4; ++m)
#pragma unroll
    for (int n = 0; n < 2; ++n) {
      const int row0 = bm * 256 + wm + m * 32 + 4 * g8;
      const int col  = bn * 256 + wn + n * 32 + l31;
#pragma unroll
      for (int reg = 0; reg < 16; ++reg) {
        int row = row0 + (reg & 3) + 8 * (reg >> 2);
        op[(size_t)row * OUT_DIM + col] = acc[m][n][reg];
      }
    }
}

// out += part, float4-vectorized
__global__ __launch_bounds__(256) void reduce_kernel(
    float* __restrict__ out, const float* __restrict__ part)
{
  size_t i = (size_t)blockIdx.x * 256 + threadIdx.x;
  float4* o = (float4*)out;
  const float4* p = (const float4*)part;
  float4 a = o[i], b = p[i];
  a.x += b.x; a.y += b.y; a.z += b.z; a.w += b.w;
  o[i] = a;
}

// ---------------- OLD fused path (fallback when workspace too small) ----------------
__global__ __launch_bounds__(256, 3) void gemm_fused_kernel(
    const float* __restrict__ X, const float* __restrict__ grid,
    const u16* __restrict__ Wt, float* __restrict__ out, float* __restrict__ part,
    int k_iters)
{
  __shared__ __align__(16) u16 As[128 * PB];
  __shared__ __align__(16) u16 Bs[128 * PB];

  const int tid  = threadIdx.x;
  const int lane = tid & 63;
  const int wave = tid >> 6;
  const int mt8  = MT * 8;
  const int s    = blockIdx.x / mt8;
  const int r    = blockIdx.x - s * mt8;
  const int bm   = r % MT;
  const int bn   = r / MT;
  const int wm = (wave >> 1) * 64;
  const int wn = (wave & 1) * 64;

  const float g0    = grid[0];
  const float inv_h = 1.0f / (grid[1] - grid[0]);

  floatx16 acc[2][2];
#pragma unroll
  for (int a = 0; a < 2; ++a)
#pragma unroll
    for (int b = 0; b < 2; ++b)
#pragma unroll
      for (int rr = 0; rr < 16; ++rr) acc[a][b][rr] = 0.f;

  const int kb_u16 = s * k_iters * BK;
  const u16* bsrc[7];
  u16*       bdst[7];
  bool       bact[7];
#pragma unroll
  for (int j = 0; j < 7; ++j) {
    int o  = wave + 4 * j;
    bact[j] = (o < NOPS);
    int oc = bact[j] ? o : (NOPS - 1);
    int gidx  = oc * 64 + lane;
    int row   = gidx / 13;
    int chunk = gidx - row * 13;
    int c8    = (chunk == 12) ? 0 : chunk;
    bsrc[j] = Wt + (size_t)(bn * 128 + row) * KDIM + kb_u16 + c8 * 8;
    bdst[j] = Bs + oc * 512;
  }

  const int arow = tid & 127;
  const int half = tid >> 7;
  const float* xp = X + (size_t)(bm * 128 + arow) * IN_DIM + s * (k_iters * 8) + half * 4;
  uint4* awp = (uint4*)(As + arow * PB + half * 48);

  const int l31 = lane & 31;
  const int g   = lane >> 5;

  float4 xv = *(const float4*)xp;

  for (int it = 0; it < k_iters; ++it) {
    uint64_t ev[12];
    expand_regs(xv.x, g0, inv_h, ev[0], ev[1], ev[2]);
    expand_regs(xv.y, g0, inv_h, ev[3], ev[4], ev[5]);
    expand_regs(xv.z, g0, inv_h, ev[6], ev[7], ev[8]);
    expand_regs(xv.w, g0, inv_h, ev[9], ev[10], ev[11]);
    if (it + 1 < k_iters) xv = *(const float4*)(xp + (size_t)(it + 1) * 8);

    __syncthreads();

#pragma unroll
    for (int j = 0; j < 7; ++j)
      if (bact[j]) async16(bsrc[j] + (size_t)it * BK, bdst[j]);

#pragma unroll
    for (int j = 0; j < 6; ++j) {
      uint4 w;
      w.x = (uint32_t)ev[2*j];     w.y = (uint32_t)(ev[2*j] >> 32);
      w.z = (uint32_t)ev[2*j+1];   w.w = (uint32_t)(ev[2*j+1] >> 32);
      awp[j] = w;
    }

    __syncthreads();

#pragma unroll
    for (int t = 0; t < 6; ++t) {
      const int cc = 2 * t + g;
      short8 af[2], bf[2];
#pragma unroll
      for (int ss2 = 0; ss2 < 2; ++ss2) {
        af[ss2] = *(const short8*)&As[(wm + ss2 * 32 + l31) * PB + cc * 8];
        bf[ss2] = *(const short8*)&Bs[(wn + ss2 * 32 + l31) * PB + cc * 8];
      }
#pragma unroll
      for (int sm = 0; sm < 2; ++sm)
#pragma unroll
        for (int sn = 0; sn < 2; ++sn)
          acc[sm][sn] = __builtin_amdgcn_mfma_f32_32x32x16_bf16(af[sm], bf[sn], acc[sm][sn], 0, 0, 0);
    }
  }
  __syncthreads();

  float* op = (s == 0) ? out : part;
#pragma unroll
  for (int sm = 0; sm < 2; ++sm)
#pragma unroll
    for (int sn = 0; sn < 2; ++sn) {
      const int row0 = bm * 128 + wm + sm * 32 + 4 * g;
      const int col  = bn * 128 + wn + sn * 32 + l31;
#pragma unroll
      for (int reg = 0; reg < 16; ++reg) {
        int row = row0 + (reg & 3) + 8 * (reg >> 2);
        op[(size_t)row * OUT_DIM + col] = acc[sm][sn][reg];
      }
    }
}

extern "C" void kernel_launch(void* const* d_in, const int* in_sizes, int n_in,
                              void* d_out, int out_size, void* d_ws, size_t ws_size,
                              hipStream_t stream) {
  const float* x     = (const float*)d_in[0];
  const float* grid  = (const float*)d_in[1];
  const float* coeff = (const float*)d_in[2];
  const float* sb    = (const float*)d_in[3];
  const float* ss    = (const float*)d_in[4];
  float* out = (float*)d_out;

  u16* Wt = (u16*)d_ws;
  const size_t wt_bytes   = (size_t)OUT_DIM * KDIM * 2;     // 25.2 MB
  const size_t aexp_bytes = (size_t)TOKENS * KDIM * 2;      // 201.3 MB
  const size_t part_bytes = (size_t)TOKENS * OUT_DIM * 4;   // 33.6 MB

  pack_wt_kernel<<<(OUT_DIM * IN_DIM) / 256, 256, 0, stream>>>(coeff, sb, ss, Wt);

  if (ws_size >= wt_bytes + aexp_bytes + part_bytes) {
    // precompute Aexp; 256x256-tile pipelined GEMM, split-K=2: 256 blocks = 1/CU
    u16*   Aexp = (u16*)((char*)d_ws + wt_bytes);
    float* part = (float*)((char*)d_ws + wt_bytes + aexp_bytes);
    expand_x_kernel<<<TOKENS / 4, 256, 0, stream>>>(x, grid, Aexp);
    gemm_pre_kernel<<<128 * 2, 512, 0, stream>>>(Aexp, Wt, out, part, 96);
    reduce_kernel<<<(TOKENS * OUT_DIM / 4) / 256, 256, 0, stream>>>(out, part);
  } else if (ws_size >= wt_bytes + aexp_bytes) {
    // precompute Aexp, no split (s==0 -> direct out), 128 blocks full-K
    u16* Aexp = (u16*)((char*)d_ws + wt_bytes);
    expand_x_kernel<<<TOKENS / 4, 256, 0, stream>>>(x, grid, Aexp);
    gemm_pre_kernel<<<128, 512, 0, stream>>>(Aexp, Wt, out, nullptr, 192);
  } else if (ws_size >= wt_bytes + part_bytes) {
    // old fused split-K=2
    float* part = (float*)((char*)d_ws + wt_bytes);
    gemm_fused_kernel<<<MT * 8 * 2, 256, 0, stream>>>(x, grid, Wt, out, part, 64);
    reduce_kernel<<<(TOKENS * OUT_DIM / 4) / 256, 256, 0, stream>>>(out, part);
  } else {
    gemm_fused_kernel<<<MT * 8, 256, 0, stream>>>(x, grid, Wt, out, nullptr, 128);
  }
}